// Round 2
// baseline (1840.594 us; speedup 1.0000x reference)
//
#include <hip/hip_runtime.h>

#define NN 100000
#define NE 3200000
#define DF 128
#define HID 32
#define NC 2

// ws layout (in floats):
// [0, NN)         dis: degree counts (float) -> rsqrt in place
// [NN, 33NN)      acc1 (edge-aggregated h1) [NN, 32]
// [33NN, 35NN)    acc2 (edge-aggregated h2) [NN, 2]
// [35NN, 67NN)    h1 = x @ W1               [NN, 32]
// total 67*NN floats = 26.8 MB; first 35*NN floats must be zeroed each call.
// h2 ([NN,2]) is staged in d_out and overwritten by k_fin2.

__global__ void k_zero(float4* __restrict__ p, int n4) {
    int stride = gridDim.x * blockDim.x;
    for (int i = blockIdx.x * blockDim.x + threadIdx.x; i < n4; i += stride)
        p[i] = make_float4(0.f, 0.f, 0.f, 0.f);
}

// count degree on dst as float (exact: partial sums are small integers)
__global__ void k_deg(const int* __restrict__ dst, float* __restrict__ dis) {
    int e = blockIdx.x * blockDim.x + threadIdx.x;
    if (e < NE) unsafeAtomicAdd(&dis[dst[e]], 1.0f);
}

__global__ void k_dis(float* __restrict__ dis) {
    int i = blockIdx.x * blockDim.x + threadIdx.x;
    if (i < NN) dis[i] = rsqrtf(dis[i] + 1.0f);  // +1 = self-loop
}

// h1 = x @ W1  (W1 accesses wave-uniform -> scalar loads; HBM-bound on x)
__global__ __launch_bounds__(256) void k_gemm1(const float* __restrict__ x,
                                               const float* __restrict__ W1,
                                               float* __restrict__ h1) {
    int r = blockIdx.x * blockDim.x + threadIdx.x;
    if (r >= NN) return;
    const float* xr = x + (size_t)r * DF;
    float acc[HID];
#pragma unroll
    for (int c = 0; c < HID; ++c) acc[c] = 0.f;
#pragma unroll
    for (int k = 0; k < DF; k += 4) {
        float4 xv = *reinterpret_cast<const float4*>(xr + k);
#pragma unroll
        for (int c = 0; c < HID; ++c) {
            acc[c] += xv.x * W1[(k + 0) * HID + c];
            acc[c] += xv.y * W1[(k + 1) * HID + c];
            acc[c] += xv.z * W1[(k + 2) * HID + c];
            acc[c] += xv.w * W1[(k + 3) * HID + c];
        }
    }
    float* hr = h1 + (size_t)r * HID;
#pragma unroll
    for (int c = 0; c < HID; c += 4)
        *reinterpret_cast<float4*>(hr + c) = make_float4(acc[c], acc[c + 1], acc[c + 2], acc[c + 3]);
}

// 8 threads per edge; each handles 4 of 32 channels (contiguous 128B gather per edge).
__global__ void k_scatter1(const int* __restrict__ eidx, const float* __restrict__ dis,
                           const float* __restrict__ h1, float* __restrict__ acc1) {
    long long t = (long long)blockIdx.x * blockDim.x + threadIdx.x;
    int e = (int)(t >> 3);
    if (e >= NE) return;
    int p = (int)t & 7;
    int s = eidx[e];
    int d = eidx[NE + e];
    float nrm = dis[s] * dis[d];
    float4 v = *reinterpret_cast<const float4*>(h1 + (size_t)s * HID + p * 4);
    float* a = acc1 + (size_t)d * HID + p * 4;
    unsafeAtomicAdd(a + 0, v.x * nrm);
    unsafeAtomicAdd(a + 1, v.y * nrm);
    unsafeAtomicAdd(a + 2, v.z * nrm);
    unsafeAtomicAdd(a + 3, v.w * nrm);
}

// h2 = relu(acc1 + self*h1 + b1) @ W2, staged into d_out
__global__ void k_fin1(const float* __restrict__ acc1, const float* __restrict__ h1,
                       const float* __restrict__ dis, const float* __restrict__ b1,
                       const float* __restrict__ W2, float* __restrict__ h2) {
    int r = blockIdx.x * blockDim.x + threadIdx.x;
    if (r >= NN) return;
    float self = dis[r] * dis[r];
    const float* ar = acc1 + (size_t)r * HID;
    const float* hr = h1 + (size_t)r * HID;
    float o0 = 0.f, o1 = 0.f;
#pragma unroll
    for (int c = 0; c < HID; c += 4) {
        float4 av = *reinterpret_cast<const float4*>(ar + c);
        float4 hv = *reinterpret_cast<const float4*>(hr + c);
        float v0 = fmaxf(av.x + hv.x * self + b1[c + 0], 0.f);
        float v1 = fmaxf(av.y + hv.y * self + b1[c + 1], 0.f);
        float v2 = fmaxf(av.z + hv.z * self + b1[c + 2], 0.f);
        float v3 = fmaxf(av.w + hv.w * self + b1[c + 3], 0.f);
        o0 += v0 * W2[(c + 0) * NC + 0] + v1 * W2[(c + 1) * NC + 0] +
              v2 * W2[(c + 2) * NC + 0] + v3 * W2[(c + 3) * NC + 0];
        o1 += v0 * W2[(c + 0) * NC + 1] + v1 * W2[(c + 1) * NC + 1] +
              v2 * W2[(c + 2) * NC + 1] + v3 * W2[(c + 3) * NC + 1];
    }
    h2[2 * (size_t)r + 0] = o0;
    h2[2 * (size_t)r + 1] = o1;
}

__global__ void k_scatter2(const int* __restrict__ eidx, const float* __restrict__ dis,
                           const float* __restrict__ h2, float* __restrict__ acc2) {
    int e = blockIdx.x * blockDim.x + threadIdx.x;
    if (e >= NE) return;
    int s = eidx[e];
    int d = eidx[NE + e];
    float nrm = dis[s] * dis[d];
    float2 v = *reinterpret_cast<const float2*>(h2 + 2 * (size_t)s);
    unsafeAtomicAdd(acc2 + 2 * (size_t)d + 0, v.x * nrm);
    unsafeAtomicAdd(acc2 + 2 * (size_t)d + 1, v.y * nrm);
}

// logits = acc2 + self*h2 + b2; out = log_softmax (reads+overwrites d_out in place)
__global__ void k_fin2(const float* __restrict__ acc2, const float* __restrict__ dis,
                       const float* __restrict__ b2, float* __restrict__ out) {
    int r = blockIdx.x * blockDim.x + threadIdx.x;
    if (r >= NN) return;
    float self = dis[r] * dis[r];
    float l0 = acc2[2 * (size_t)r + 0] + out[2 * (size_t)r + 0] * self + b2[0];
    float l1 = acc2[2 * (size_t)r + 1] + out[2 * (size_t)r + 1] * self + b2[1];
    float m = fmaxf(l0, l1);
    float lse = m + logf(expf(l0 - m) + expf(l1 - m));
    out[2 * (size_t)r + 0] = l0 - lse;
    out[2 * (size_t)r + 1] = l1 - lse;
}

extern "C" void kernel_launch(void* const* d_in, const int* in_sizes, int n_in,
                              void* d_out, int out_size, void* d_ws, size_t ws_size,
                              hipStream_t stream) {
    const float* x  = (const float*)d_in[0];
    const int* ei   = (const int*)d_in[1];   // [2, NE], harness delivers integers as int32
    const float* W1 = (const float*)d_in[2];
    const float* b1 = (const float*)d_in[3];
    const float* W2 = (const float*)d_in[4];
    const float* b2 = (const float*)d_in[5];
    float* out      = (float*)d_out;

    float* ws   = (float*)d_ws;
    float* dis  = ws;
    float* acc1 = ws + (size_t)NN;
    float* acc2 = ws + (size_t)33 * NN;
    float* h1   = ws + (size_t)35 * NN;

    k_zero<<<2048, 256, 0, stream>>>((float4*)d_ws, (35 * NN) / 4);
    k_deg<<<(NE + 255) / 256, 256, 0, stream>>>(ei + NE, dis);
    k_dis<<<(NN + 255) / 256, 256, 0, stream>>>(dis);
    k_gemm1<<<(NN + 255) / 256, 256, 0, stream>>>(x, W1, h1);
    {
        long long threads = (long long)NE * 8;
        int blocks = (int)((threads + 255) / 256);
        k_scatter1<<<blocks, 256, 0, stream>>>(ei, dis, h1, acc1);
    }
    k_fin1<<<(NN + 255) / 256, 256, 0, stream>>>(acc1, h1, dis, b1, W2, out);
    k_scatter2<<<(NE + 255) / 256, 256, 0, stream>>>(ei, dis, out, acc2);
    k_fin2<<<(NN + 255) / 256, 256, 0, stream>>>(acc2, dis, b2, out);
}

// Round 3
// 570.063 us; speedup vs baseline: 3.2288x; 3.2288x over previous
//
#include <hip/hip_runtime.h>

#define NN 100000
#define NE 3200000
#define DF 128
#define HID 32
#define NC 2
#define NB 391   // ceil(NN/256)

// ws layout (4-byte units):
// [0, NN)               dis (float): rsqrt(deg+1)
// [NN, 2NN)             rofs (int): counts -> exclusive scan -> (after fill) row ENDS
// [2NN, 2NN+1024)       bsum (int): per-block scan sums
// [2NN+1024, 4NN+1024)  h2 (float [NN,2])
// [4NN+1024, +NE)       csr (int): src indices grouped by dst
// [..., +32NN)          h1 (float [NN,32])
// total 36NN + NE + 1024 = 6,801,024 words = 27.2 MB (< 28 MB proven available)

__global__ void k_zero(int4* __restrict__ p, int n4) {
    int i = blockIdx.x * blockDim.x + threadIdx.x;
    if (i < n4) p[i] = make_int4(0, 0, 0, 0);
}

__global__ void k_count(const int* __restrict__ dst, unsigned* __restrict__ cnt) {
    int e = blockIdx.x * blockDim.x + threadIdx.x;
    if (e < NE) atomicAdd(&cnt[dst[e]], 1u);
}

// in-place per-block exclusive scan of counts; block totals -> bsum
__global__ void k_scan1(int* __restrict__ rofs, int* __restrict__ bsum) {
    __shared__ int sm[256];
    int i = blockIdx.x * 256 + threadIdx.x;
    int v = (i < NN) ? rofs[i] : 0;
    sm[threadIdx.x] = v;
    __syncthreads();
    for (int off = 1; off < 256; off <<= 1) {
        int t = (threadIdx.x >= off) ? sm[threadIdx.x - off] : 0;
        __syncthreads();
        sm[threadIdx.x] += t;
        __syncthreads();
    }
    if (i < NN) rofs[i] = sm[threadIdx.x] - v;  // exclusive
    if (threadIdx.x == 255) bsum[blockIdx.x] = sm[255];
}

// single-block scan of the NB block sums -> exclusive
__global__ void k_scan2(int* __restrict__ bsum) {
    __shared__ int sm[512];
    int v = (threadIdx.x < NB) ? bsum[threadIdx.x] : 0;
    sm[threadIdx.x] = v;
    __syncthreads();
    for (int off = 1; off < 512; off <<= 1) {
        int t = (threadIdx.x >= off) ? sm[threadIdx.x - off] : 0;
        __syncthreads();
        sm[threadIdx.x] += t;
        __syncthreads();
    }
    if (threadIdx.x < NB) bsum[threadIdx.x] = sm[threadIdx.x] - v;
}

__global__ void k_scan3(int* __restrict__ rofs, const int* __restrict__ bsum) {
    int i = blockIdx.x * 256 + threadIdx.x;
    if (i < NN) rofs[i] += bsum[blockIdx.x];
}

// dis from adjacent diffs (must run after scan, before fill mutates rofs)
__global__ void k_dis(const int* __restrict__ rofs, float* __restrict__ dis) {
    int i = blockIdx.x * 256 + threadIdx.x;
    if (i >= NN) return;
    int nxt = (i == NN - 1) ? NE : rofs[i + 1];
    dis[i] = rsqrtf((float)(nxt - rofs[i] + 1));  // +1 = self-loop
}

// counting-sort fill: rofs becomes row ENDS afterwards
__global__ void k_fill(const int* __restrict__ eidx, unsigned* __restrict__ cursor,
                       int* __restrict__ csr) {
    int e = blockIdx.x * blockDim.x + threadIdx.x;
    if (e >= NE) return;
    int s = eidx[e];
    int d = eidx[NE + e];
    unsigned pos = atomicAdd(&cursor[d], 1u);
    csr[pos] = s;
}

// h1 = x @ W1 (W1 wave-uniform -> scalar loads; HBM-bound on x)
__global__ __launch_bounds__(256) void k_gemm1(const float* __restrict__ x,
                                               const float* __restrict__ W1,
                                               float* __restrict__ h1) {
    int r = blockIdx.x * blockDim.x + threadIdx.x;
    if (r >= NN) return;
    const float* xr = x + (size_t)r * DF;
    float acc[HID];
#pragma unroll
    for (int c = 0; c < HID; ++c) acc[c] = 0.f;
#pragma unroll
    for (int k = 0; k < DF; k += 4) {
        float4 xv = *reinterpret_cast<const float4*>(xr + k);
#pragma unroll
        for (int c = 0; c < HID; ++c) {
            acc[c] += xv.x * W1[(k + 0) * HID + c];
            acc[c] += xv.y * W1[(k + 1) * HID + c];
            acc[c] += xv.z * W1[(k + 2) * HID + c];
            acc[c] += xv.w * W1[(k + 3) * HID + c];
        }
    }
    float* hr = h1 + (size_t)r * HID;
#pragma unroll
    for (int c = 0; c < HID; c += 4)
        *reinterpret_cast<float4*>(hr + c) = make_float4(acc[c], acc[c + 1], acc[c + 2], acc[c + 3]);
}

// gather-aggregate layer 1, fused with +b1, relu, @W2, 8-lane reduce -> h2
__global__ void k_gather1(const int* __restrict__ rofs, const int* __restrict__ csr,
                          const float* __restrict__ dis, const float* __restrict__ h1,
                          const float* __restrict__ b1, const float* __restrict__ W2,
                          float* __restrict__ h2) {
    int t = blockIdx.x * blockDim.x + threadIdx.x;
    int r = t >> 3;
    if (r >= NN) return;
    int p = t & 7;
    int end = rofs[r];                    // post-fill: rofs[r] = end of row r
    int start = (r == 0) ? 0 : rofs[r - 1];
    float dr = dis[r];
    float a0 = 0.f, a1 = 0.f, a2 = 0.f, a3 = 0.f;
    int j = start;
    for (; j + 1 < end; j += 2) {         // 2-wide for gather MLP
        int s0 = csr[j], s1 = csr[j + 1];
        float n0 = dr * dis[s0], n1 = dr * dis[s1];
        float4 v0 = *reinterpret_cast<const float4*>(h1 + (size_t)s0 * HID + p * 4);
        float4 v1 = *reinterpret_cast<const float4*>(h1 + (size_t)s1 * HID + p * 4);
        a0 += v0.x * n0 + v1.x * n1;
        a1 += v0.y * n0 + v1.y * n1;
        a2 += v0.z * n0 + v1.z * n1;
        a3 += v0.w * n0 + v1.w * n1;
    }
    if (j < end) {
        int s0 = csr[j];
        float n0 = dr * dis[s0];
        float4 v0 = *reinterpret_cast<const float4*>(h1 + (size_t)s0 * HID + p * 4);
        a0 += v0.x * n0; a1 += v0.y * n0; a2 += v0.z * n0; a3 += v0.w * n0;
    }
    // self-loop
    float self = dr * dr;
    float4 hv = *reinterpret_cast<const float4*>(h1 + (size_t)r * HID + p * 4);
    a0 += hv.x * self; a1 += hv.y * self; a2 += hv.z * self; a3 += hv.w * self;
    // + b1, relu
    float4 bv = *reinterpret_cast<const float4*>(b1 + p * 4);
    float v0 = fmaxf(a0 + bv.x, 0.f);
    float v1 = fmaxf(a1 + bv.y, 0.f);
    float v2 = fmaxf(a2 + bv.z, 0.f);
    float v3 = fmaxf(a3 + bv.w, 0.f);
    // @ W2 (rows p*4 .. p*4+3)
    int c = p * 4;
    float o0 = v0 * W2[(c + 0) * NC + 0] + v1 * W2[(c + 1) * NC + 0] +
               v2 * W2[(c + 2) * NC + 0] + v3 * W2[(c + 3) * NC + 0];
    float o1 = v0 * W2[(c + 0) * NC + 1] + v1 * W2[(c + 1) * NC + 1] +
               v2 * W2[(c + 2) * NC + 1] + v3 * W2[(c + 3) * NC + 1];
    // reduce across the 8-lane group
    o0 += __shfl_xor(o0, 1); o1 += __shfl_xor(o1, 1);
    o0 += __shfl_xor(o0, 2); o1 += __shfl_xor(o1, 2);
    o0 += __shfl_xor(o0, 4); o1 += __shfl_xor(o1, 4);
    if (p == 0) {
        h2[2 * (size_t)r + 0] = o0;
        h2[2 * (size_t)r + 1] = o1;
    }
}

// gather-aggregate layer 2 (+b2) fused with log_softmax -> out
__global__ void k_gather2(const int* __restrict__ rofs, const int* __restrict__ csr,
                          const float* __restrict__ dis, const float* __restrict__ h2,
                          const float* __restrict__ b2, float* __restrict__ out) {
    int r = blockIdx.x * blockDim.x + threadIdx.x;
    if (r >= NN) return;
    int end = rofs[r];
    int start = (r == 0) ? 0 : rofs[r - 1];
    float dr = dis[r];
    float a0 = 0.f, a1 = 0.f;
    for (int j = start; j < end; ++j) {
        int s = csr[j];
        float nrm = dr * dis[s];
        float2 v = *reinterpret_cast<const float2*>(h2 + 2 * (size_t)s);
        a0 += v.x * nrm;
        a1 += v.y * nrm;
    }
    float self = dr * dr;
    float2 hv = *reinterpret_cast<const float2*>(h2 + 2 * (size_t)r);
    float l0 = a0 + hv.x * self + b2[0];
    float l1 = a1 + hv.y * self + b2[1];
    float m = fmaxf(l0, l1);
    float lse = m + logf(expf(l0 - m) + expf(l1 - m));
    out[2 * (size_t)r + 0] = l0 - lse;
    out[2 * (size_t)r + 1] = l1 - lse;
}

extern "C" void kernel_launch(void* const* d_in, const int* in_sizes, int n_in,
                              void* d_out, int out_size, void* d_ws, size_t ws_size,
                              hipStream_t stream) {
    const float* x  = (const float*)d_in[0];
    const int* ei   = (const int*)d_in[1];   // [2, NE] int32
    const float* W1 = (const float*)d_in[2];
    const float* b1 = (const float*)d_in[3];
    const float* W2 = (const float*)d_in[4];
    const float* b2 = (const float*)d_in[5];
    float* out      = (float*)d_out;

    float* ws  = (float*)d_ws;
    float* dis = ws;
    int* rofs  = (int*)(ws + (size_t)NN);
    int* bsum  = (int*)(ws + (size_t)2 * NN);
    float* h2  = ws + (size_t)2 * NN + 1024;
    int* csr   = (int*)(ws + (size_t)4 * NN + 1024);
    float* h1  = ws + (size_t)4 * NN + 1024 + NE;

    k_zero<<<(NN / 4 + 255) / 256, 256, 0, stream>>>((int4*)rofs, NN / 4);
    k_count<<<(NE + 255) / 256, 256, 0, stream>>>(ei + NE, (unsigned*)rofs);
    k_scan1<<<NB, 256, 0, stream>>>(rofs, bsum);
    k_scan2<<<1, 512, 0, stream>>>(bsum);
    k_scan3<<<NB, 256, 0, stream>>>(rofs, bsum);
    k_dis<<<NB, 256, 0, stream>>>(rofs, dis);
    k_gemm1<<<NB, 256, 0, stream>>>(x, W1, h1);
    k_fill<<<(NE + 255) / 256, 256, 0, stream>>>(ei, (unsigned*)rofs, csr);
    k_gather1<<<(NN * 8 + 255) / 256, 256, 0, stream>>>(rofs, csr, dis, h1, b1, W2, h2);
    k_gather2<<<NB, 256, 0, stream>>>(rofs, csr, dis, h2, b2, out);
}

// Round 4
// 346.515 us; speedup vs baseline: 5.3117x; 1.6451x over previous
//
#include <hip/hip_runtime.h>

#define NN 100000
#define NE 3200000
#define DF 128
#define HID 32
#define NC 2
#define NB 391   // ceil(NN/256)

// ws layout (4-byte words):
// [0, NN)               dis (float): rsqrt(deg+1)
// [NN, 2NN)             rofs (int): counts -> exclusive scan = row STARTS (never mutated after)
// [2NN, 2NN+1024)       bsum (int): per-block scan sums
// [2NN+1024, 4NN+1024)  h2 (float [NN,2])
// [4NN+1024, +NE)       csr (int): src indices grouped by dst
// [4NN+1024+NE, +32NN)  h1 (float [NN,32]); first NE words double as rank[] until k_gemm1
// total 36NN + NE + 1024 = 27.2 MB (unchanged, proven available)

__global__ void k_zero(int4* __restrict__ p, int n4) {
    int i = blockIdx.x * blockDim.x + threadIdx.x;
    if (i < n4) p[i] = make_int4(0, 0, 0, 0);
}

// count degree AND record each edge's rank within its dst (atomics paid once)
__global__ void k_rank(const int* __restrict__ dst, unsigned* __restrict__ cnt,
                       int* __restrict__ rank) {
    int e = blockIdx.x * blockDim.x + threadIdx.x;
    if (e < NE) rank[e] = (int)atomicAdd(&cnt[dst[e]], 1u);
}

// in-place per-block exclusive scan of counts; block totals -> bsum
__global__ void k_scan1(int* __restrict__ rofs, int* __restrict__ bsum) {
    __shared__ int sm[256];
    int i = blockIdx.x * 256 + threadIdx.x;
    int v = (i < NN) ? rofs[i] : 0;
    sm[threadIdx.x] = v;
    __syncthreads();
    for (int off = 1; off < 256; off <<= 1) {
        int t = (threadIdx.x >= off) ? sm[threadIdx.x - off] : 0;
        __syncthreads();
        sm[threadIdx.x] += t;
        __syncthreads();
    }
    if (i < NN) rofs[i] = sm[threadIdx.x] - v;  // exclusive
    if (threadIdx.x == 255) bsum[blockIdx.x] = sm[255];
}

__global__ void k_scan2(int* __restrict__ bsum) {
    __shared__ int sm[512];
    int v = (threadIdx.x < NB) ? bsum[threadIdx.x] : 0;
    sm[threadIdx.x] = v;
    __syncthreads();
    for (int off = 1; off < 512; off <<= 1) {
        int t = (threadIdx.x >= off) ? sm[threadIdx.x - off] : 0;
        __syncthreads();
        sm[threadIdx.x] += t;
        __syncthreads();
    }
    if (threadIdx.x < NB) bsum[threadIdx.x] = sm[threadIdx.x] - v;
}

__global__ void k_scan3(int* __restrict__ rofs, const int* __restrict__ bsum) {
    int i = blockIdx.x * 256 + threadIdx.x;
    if (i < NN) rofs[i] += bsum[blockIdx.x];
}

__global__ void k_dis(const int* __restrict__ rofs, float* __restrict__ dis) {
    int i = blockIdx.x * 256 + threadIdx.x;
    if (i >= NN) return;
    int nxt = (i == NN - 1) ? NE : rofs[i + 1];
    dis[i] = rsqrtf((float)(nxt - rofs[i] + 1));  // +1 = self-loop
}

// atomic-free CSR fill: independent scattered writes only
__global__ void k_fill(const int* __restrict__ eidx, const int* __restrict__ rofs,
                       const int* __restrict__ rank, int* __restrict__ csr) {
    int e = blockIdx.x * blockDim.x + threadIdx.x;
    if (e >= NE) return;
    int s = eidx[e];
    int d = eidx[NE + e];
    csr[rofs[d] + rank[e]] = s;
}

// h1 = x @ W1 (W1 wave-uniform -> scalar loads; HBM-bound on x)
__global__ __launch_bounds__(256) void k_gemm1(const float* __restrict__ x,
                                               const float* __restrict__ W1,
                                               float* __restrict__ h1) {
    int r = blockIdx.x * blockDim.x + threadIdx.x;
    if (r >= NN) return;
    const float* xr = x + (size_t)r * DF;
    float acc[HID];
#pragma unroll
    for (int c = 0; c < HID; ++c) acc[c] = 0.f;
#pragma unroll
    for (int k = 0; k < DF; k += 4) {
        float4 xv = *reinterpret_cast<const float4*>(xr + k);
#pragma unroll
        for (int c = 0; c < HID; ++c) {
            acc[c] += xv.x * W1[(k + 0) * HID + c];
            acc[c] += xv.y * W1[(k + 1) * HID + c];
            acc[c] += xv.z * W1[(k + 2) * HID + c];
            acc[c] += xv.w * W1[(k + 3) * HID + c];
        }
    }
    float* hr = h1 + (size_t)r * HID;
#pragma unroll
    for (int c = 0; c < HID; c += 4)
        *reinterpret_cast<float4*>(hr + c) = make_float4(acc[c], acc[c + 1], acc[c + 2], acc[c + 3]);
}

// gather-aggregate layer 1, fused with +b1, relu, @W2, 8-lane reduce -> h2
__global__ void k_gather1(const int* __restrict__ rofs, const int* __restrict__ csr,
                          const float* __restrict__ dis, const float* __restrict__ h1,
                          const float* __restrict__ b1, const float* __restrict__ W2,
                          float* __restrict__ h2) {
    int t = blockIdx.x * blockDim.x + threadIdx.x;
    int r = t >> 3;
    if (r >= NN) return;
    int p = t & 7;
    int start = rofs[r];
    int end = (r == NN - 1) ? NE : rofs[r + 1];
    float dr = dis[r];
    float a0 = 0.f, a1 = 0.f, a2 = 0.f, a3 = 0.f;
    int j = start;
    for (; j + 1 < end; j += 2) {
        int s0 = csr[j], s1 = csr[j + 1];
        float n0 = dr * dis[s0], n1 = dr * dis[s1];
        float4 v0 = *reinterpret_cast<const float4*>(h1 + (size_t)s0 * HID + p * 4);
        float4 v1 = *reinterpret_cast<const float4*>(h1 + (size_t)s1 * HID + p * 4);
        a0 += v0.x * n0 + v1.x * n1;
        a1 += v0.y * n0 + v1.y * n1;
        a2 += v0.z * n0 + v1.z * n1;
        a3 += v0.w * n0 + v1.w * n1;
    }
    if (j < end) {
        int s0 = csr[j];
        float n0 = dr * dis[s0];
        float4 v0 = *reinterpret_cast<const float4*>(h1 + (size_t)s0 * HID + p * 4);
        a0 += v0.x * n0; a1 += v0.y * n0; a2 += v0.z * n0; a3 += v0.w * n0;
    }
    float self = dr * dr;
    float4 hv = *reinterpret_cast<const float4*>(h1 + (size_t)r * HID + p * 4);
    a0 += hv.x * self; a1 += hv.y * self; a2 += hv.z * self; a3 += hv.w * self;
    float4 bv = *reinterpret_cast<const float4*>(b1 + p * 4);
    float v0 = fmaxf(a0 + bv.x, 0.f);
    float v1 = fmaxf(a1 + bv.y, 0.f);
    float v2 = fmaxf(a2 + bv.z, 0.f);
    float v3 = fmaxf(a3 + bv.w, 0.f);
    int c = p * 4;
    float o0 = v0 * W2[(c + 0) * NC + 0] + v1 * W2[(c + 1) * NC + 0] +
               v2 * W2[(c + 2) * NC + 0] + v3 * W2[(c + 3) * NC + 0];
    float o1 = v0 * W2[(c + 0) * NC + 1] + v1 * W2[(c + 1) * NC + 1] +
               v2 * W2[(c + 2) * NC + 1] + v3 * W2[(c + 3) * NC + 1];
    o0 += __shfl_xor(o0, 1); o1 += __shfl_xor(o1, 1);
    o0 += __shfl_xor(o0, 2); o1 += __shfl_xor(o1, 2);
    o0 += __shfl_xor(o0, 4); o1 += __shfl_xor(o1, 4);
    if (p == 0) {
        h2[2 * (size_t)r + 0] = o0;
        h2[2 * (size_t)r + 1] = o1;
    }
}

// gather-aggregate layer 2 (+b2) fused with log_softmax -> out
__global__ void k_gather2(const int* __restrict__ rofs, const int* __restrict__ csr,
                          const float* __restrict__ dis, const float* __restrict__ h2,
                          const float* __restrict__ b2, float* __restrict__ out) {
    int r = blockIdx.x * blockDim.x + threadIdx.x;
    if (r >= NN) return;
    int start = rofs[r];
    int end = (r == NN - 1) ? NE : rofs[r + 1];
    float dr = dis[r];
    float a0 = 0.f, a1 = 0.f;
    for (int j = start; j < end; ++j) {
        int s = csr[j];
        float nrm = dr * dis[s];
        float2 v = *reinterpret_cast<const float2*>(h2 + 2 * (size_t)s);
        a0 += v.x * nrm;
        a1 += v.y * nrm;
    }
    float self = dr * dr;
    float2 hv = *reinterpret_cast<const float2*>(h2 + 2 * (size_t)r);
    float l0 = a0 + hv.x * self + b2[0];
    float l1 = a1 + hv.y * self + b2[1];
    float m = fmaxf(l0, l1);
    float lse = m + logf(expf(l0 - m) + expf(l1 - m));
    out[2 * (size_t)r + 0] = l0 - lse;
    out[2 * (size_t)r + 1] = l1 - lse;
}

extern "C" void kernel_launch(void* const* d_in, const int* in_sizes, int n_in,
                              void* d_out, int out_size, void* d_ws, size_t ws_size,
                              hipStream_t stream) {
    const float* x  = (const float*)d_in[0];
    const int* ei   = (const int*)d_in[1];   // [2, NE] int32
    const float* W1 = (const float*)d_in[2];
    const float* b1 = (const float*)d_in[3];
    const float* W2 = (const float*)d_in[4];
    const float* b2 = (const float*)d_in[5];
    float* out      = (float*)d_out;

    float* ws  = (float*)d_ws;
    float* dis = ws;
    int* rofs  = (int*)(ws + (size_t)NN);
    int* bsum  = (int*)(ws + (size_t)2 * NN);
    float* h2  = ws + (size_t)2 * NN + 1024;
    int* csr   = (int*)(ws + (size_t)4 * NN + 1024);
    float* h1  = ws + (size_t)4 * NN + 1024 + NE;
    int* rank  = (int*)h1;   // NE words; dead before k_gemm1 writes h1

    k_zero<<<(NN / 4 + 255) / 256, 256, 0, stream>>>((int4*)rofs, NN / 4);
    k_rank<<<(NE + 255) / 256, 256, 0, stream>>>(ei + NE, (unsigned*)rofs, rank);
    k_scan1<<<NB, 256, 0, stream>>>(rofs, bsum);
    k_scan2<<<1, 512, 0, stream>>>(bsum);
    k_scan3<<<NB, 256, 0, stream>>>(rofs, bsum);
    k_dis<<<NB, 256, 0, stream>>>(rofs, dis);
    k_fill<<<(NE + 255) / 256, 256, 0, stream>>>(ei, rofs, rank, csr);
    k_gemm1<<<NB, 256, 0, stream>>>(x, W1, h1);
    k_gather1<<<(NN * 8 + 255) / 256, 256, 0, stream>>>(rofs, csr, dis, h1, b1, W2, h2);
    k_gather2<<<NB, 256, 0, stream>>>(rofs, csr, dis, h2, b2, out);
}